// Round 1
// baseline (544.246 us; speedup 1.0000x reference)
//
#include <hip/hip_runtime.h>
#include <math.h>

// Problem constants (fixed-shape problem)
#define NROWS 4096
#define DFEA  512
#define NCLS  751
#define DSIDE 1024

__device__ __forceinline__ float wave_sum(float v) {
#pragma unroll
  for (int off = 32; off > 0; off >>= 1) v += __shfl_xor(v, off, 64);
  return v;
}

// ---------------- accumulator zeroing ----------------
__global__ __launch_bounds__(64) void k_zero(float* __restrict__ accw) {
  if (threadIdx.x < 16) accw[threadIdx.x] = 0.0f;
}

// ---------------- per-row sum-of-squares + top1 accuracy ----------------
// one wave per row; 4 rows per 256-thread block
__global__ __launch_bounds__(256) void k_row_sq_acc(const float* __restrict__ fea,
                                                    const int* __restrict__ tgt,
                                                    float* __restrict__ sq,
                                                    float* __restrict__ accw) {
  const int lane = threadIdx.x & 63;
  const int wid  = threadIdx.x >> 6;
  const int row  = blockIdx.x * 4 + wid;
  const float* x = fea + (size_t)row * DFEA;
  float s = 0.0f, bv = -1e30f;
  int bi = 0;
#pragma unroll
  for (int q = 0; q < DFEA / 64; ++q) {
    const int c = lane + q * 64;
    const float v = x[c];
    s += v * v;
    if (v > bv) { bv = v; bi = c; }
  }
#pragma unroll
  for (int off = 32; off > 0; off >>= 1) {
    s += __shfl_xor(s, off, 64);
    const float ov = __shfl_xor(bv, off, 64);
    const int   oi = __shfl_xor(bi, off, 64);
    if (ov > bv || (ov == bv && oi < bi)) { bv = ov; bi = oi; }  // argmax, first-index on tie
  }
  __shared__ float red[4];
  if (lane == 0) {
    sq[row]  = s;
    red[wid] = (bi == tgt[row]) ? 1.0f : 0.0f;
  }
  __syncthreads();
  if (threadIdx.x == 0) atomicAdd(&accw[5], red[0] + red[1] + red[2] + red[3]);
}

// ---------------- fused distance GEMM + per-row negative top-8 mining ----------------
// grid (8 col-groups, 64 row-blocks), 256 threads.
// Block handles 64 rows x 512 cols; maintains per-thread register top-8 of negative
// distances, merges across threads in LDS, writes per-(row,group) sorted partial top-8.
// The group that contains a row's positive 8-block stashes those 8 distances separately.
__global__ __launch_bounds__(256) void k_gemm_mine(const float* __restrict__ fea,
                                                   const float* __restrict__ sq,
                                                   float* __restrict__ posw,
                                                   float* __restrict__ part) {
  const int g   = blockIdx.x;   // 0..7
  const int b   = blockIdx.y;   // 0..63
  const int tid = threadIdx.x;
  const int tx  = tid & 15, ty = tid >> 4;
  const int R0  = b * 64, C0 = g * 512;
  const int posg = b >> 3;      // the col-group holding this row-block's positives

  __shared__ float As[32][64];         // [k][row], 8KB
  __shared__ float Bs[32][64];         // [k][col], 8KB
  __shared__ float mrg[64 * 16 * 8];   // 32KB merge buffer
  __shared__ float posb[64][8];        // 2KB positive distances

  float sqi[4];
#pragma unroll
  for (int ri = 0; ri < 4; ++ri) sqi[ri] = sq[R0 + ty * 4 + ri];

  float top8[4][8];                    // sorted ascending, [7] is max
#pragma unroll
  for (int ri = 0; ri < 4; ++ri)
#pragma unroll
    for (int q = 0; q < 8; ++q) top8[ri][q] = 1e30f;

  const int rA = tid >> 3;             // 0..31 (and +32)
  const int k4 = (tid & 7) << 2;       // 0,4,...,28

  for (int ct = 0; ct < 8; ++ct) {     // 8 col tiles of 64
    float dot[4][4];
#pragma unroll
    for (int ri = 0; ri < 4; ++ri)
#pragma unroll
      for (int ci = 0; ci < 4; ++ci) dot[ri][ci] = 0.0f;
    const int CT0 = C0 + ct * 64;

    for (int kt = 0; kt < DFEA; kt += 32) {
      __syncthreads();  // protect LDS from previous inner loop
      const float4 a0 = *(const float4*)&fea[(size_t)(R0 + rA)      * DFEA + kt + k4];
      const float4 a1 = *(const float4*)&fea[(size_t)(R0 + rA + 32) * DFEA + kt + k4];
      const float4 b0 = *(const float4*)&fea[(size_t)(CT0 + rA)      * DFEA + kt + k4];
      const float4 b1 = *(const float4*)&fea[(size_t)(CT0 + rA + 32) * DFEA + kt + k4];
      As[k4 + 0][rA] = a0.x; As[k4 + 1][rA] = a0.y; As[k4 + 2][rA] = a0.z; As[k4 + 3][rA] = a0.w;
      As[k4 + 0][rA + 32] = a1.x; As[k4 + 1][rA + 32] = a1.y; As[k4 + 2][rA + 32] = a1.z; As[k4 + 3][rA + 32] = a1.w;
      Bs[k4 + 0][rA] = b0.x; Bs[k4 + 1][rA] = b0.y; Bs[k4 + 2][rA] = b0.z; Bs[k4 + 3][rA] = b0.w;
      Bs[k4 + 0][rA + 32] = b1.x; Bs[k4 + 1][rA + 32] = b1.y; Bs[k4 + 2][rA + 32] = b1.z; Bs[k4 + 3][rA + 32] = b1.w;
      __syncthreads();
#pragma unroll
      for (int k = 0; k < 32; ++k) {
        const float4 av = *(const float4*)&As[k][ty * 4];
        const float4 bv = *(const float4*)&Bs[k][tx * 4];
        const float a_[4] = {av.x, av.y, av.z, av.w};
        const float b_[4] = {bv.x, bv.y, bv.z, bv.w};
#pragma unroll
        for (int ri = 0; ri < 4; ++ri)
#pragma unroll
          for (int ci = 0; ci < 4; ++ci) dot[ri][ci] = fmaf(a_[ri], b_[ci], dot[ri][ci]);
      }
    }

    // distances + mining for this 64x64 tile
#pragma unroll
    for (int ci = 0; ci < 4; ++ci) {
      const int jloc = ct * 64 + tx * 4 + ci;
      const float sqj = sq[CT0 + tx * 4 + ci];
#pragma unroll
      for (int ri = 0; ri < 4; ++ri) {
        const int r = ty * 4 + ri;
        const float d2   = sqi[ri] + sqj - 2.0f * dot[ri][ci];
        const float dist = sqrtf(fmaxf(d2, 1e-12f));
        const bool isPos = (g == posg) && ((jloc >> 3) == (((b & 7) << 3) + (r >> 3)));
        if (isPos) {
          posb[r][jloc & 7] = dist;
        } else if (dist < top8[ri][7]) {
          float x = dist;
#pragma unroll
          for (int q = 0; q < 8; ++q) {
            const float lo = fminf(top8[ri][q], x);
            x = fmaxf(top8[ri][q], x);
            top8[ri][q] = lo;
          }
        }
      }
    }
  }

  __syncthreads();
#pragma unroll
  for (int ri = 0; ri < 4; ++ri)
#pragma unroll
    for (int q = 0; q < 8; ++q)
      mrg[((ty * 4 + ri) * 16 + tx) * 8 + q] = top8[ri][q];
  __syncthreads();

  if (tid < 64) {
    const int r = tid;
    float n8[8];
#pragma unroll
    for (int q = 0; q < 8; ++q) n8[q] = 1e30f;
    for (int t = 0; t < 16; ++t) {
      for (int q = 0; q < 8; ++q) {
        const float v = mrg[(r * 16 + t) * 8 + q];
        if (v >= n8[7]) break;  // each list is sorted ascending
        float x = v;
#pragma unroll
        for (int s2 = 0; s2 < 8; ++s2) {
          const float lo = fminf(n8[s2], x);
          x = fmaxf(n8[s2], x);
          n8[s2] = lo;
        }
      }
    }
#pragma unroll
    for (int q = 0; q < 8; ++q) part[((size_t)(R0 + r) * 8 + g) * 8 + q] = n8[q];
    if (g == posg) {
#pragma unroll
      for (int q = 0; q < 8; ++q) posw[(size_t)(R0 + r) * 8 + q] = posb[r][q];
    }
  }
}

// ---------------- final per-row merge + rank loss ----------------
__global__ __launch_bounds__(256) void k_final_mine(const float* __restrict__ part,
                                                    const float* __restrict__ posw,
                                                    float* __restrict__ accw) {
  const int i = blockIdx.x * 256 + threadIdx.x;  // row
  float n8[8];
#pragma unroll
  for (int q = 0; q < 8; ++q) n8[q] = 1e30f;
  for (int t = 0; t < 64; ++t) {   // 8 groups x 8 sorted partials
    const float v = part[(size_t)i * 64 + t];
    if (v < n8[7]) {
      float x = v;
#pragma unroll
      for (int s = 0; s < 8; ++s) {
        const float lo = fminf(n8[s], x);
        x = fmaxf(n8[s], x);
        n8[s] = lo;
      }
    }
  }
  float p8[8];
#pragma unroll
  for (int q = 0; q < 8; ++q) p8[q] = posw[(size_t)i * 8 + q];
  // odd-even sort p8 ascending (branchless)
#pragma unroll
  for (int pass = 0; pass < 8; ++pass) {
    const int st = pass & 1;
#pragma unroll
    for (int c = 0; c < 7; ++c) {
      if ((c & 1) == st) {
        const float lo = fminf(p8[c], p8[c + 1]);
        const float hi = fmaxf(p8[c], p8[c + 1]);
        p8[c] = lo; p8[c + 1] = hi;
      }
    }
  }
  // m = #negatives among the 8 smallest of union(p8, n8)
  int ip = 0, in_ = 0;
#pragma unroll
  for (int s = 0; s < 8; ++s) {
    const bool takeNeg = (in_ < 8) && (ip >= 8 || n8[in_] < p8[ip]);
    if (takeNeg) ++in_; else ++ip;
  }
  const int m = in_;
  float loss = 0.0f;
  const float n0 = n8[0];
  for (int k = 0; k < m; ++k) {
    const float w = (float)(m - k) * expf((n0 - n8[k]) / (n0 + 1e-12f));
    loss += w * (p8[7 - k] - n8[k]) + 0.5f;
  }
  float corr = (m == 0) ? 1.0f : 0.0f;
  loss = wave_sum(loss);
  corr = wave_sum(corr);
  __shared__ float red[8];
  const int wid = threadIdx.x >> 6, lane = threadIdx.x & 63;
  if (lane == 0) { red[wid] = loss; red[4 + wid] = corr; }
  __syncthreads();
  if (threadIdx.x == 0) {
    atomicAdd(&accw[0], red[0] + red[1] + red[2] + red[3]);
    atomicAdd(&accw[1], red[4] + red[5] + red[6] + red[7]);
  }
}

// ---------------- cross entropy (one wave per row) ----------------
__global__ __launch_bounds__(256) void k_xent(const float* __restrict__ cls,
                                              const int* __restrict__ tgt,
                                              float* __restrict__ accw) {
  const int lane = threadIdx.x & 63, wid = threadIdx.x >> 6;
  const int row = blockIdx.x * 4 + wid;
  const float* x = cls + (size_t)row * NCLS;
  float mx = -1e30f;
  for (int c = lane; c < NCLS; c += 64) mx = fmaxf(mx, x[c]);
#pragma unroll
  for (int off = 32; off > 0; off >>= 1) mx = fmaxf(mx, __shfl_xor(mx, off, 64));
  float se = 0.0f;
  for (int c = lane; c < NCLS; c += 64) se += expf(x[c] - mx);
  se = wave_sum(se);
  __shared__ float red[4];
  if (lane == 0) red[wid] = logf(se) + mx - x[tgt[row]];
  __syncthreads();
  if (threadIdx.x == 0) atomicAdd(&accw[2], red[0] + red[1] + red[2] + red[3]);
}

// ---------------- side losses: ||l4-l2||_F^2 and ||l4-l3||_F^2 ----------------
__global__ __launch_bounds__(256) void k_side(const float* __restrict__ l2,
                                              const float* __restrict__ l3,
                                              const float* __restrict__ l4,
                                              float* __restrict__ accw) {
  const int nt = gridDim.x * blockDim.x;
  float s2 = 0.0f, s3 = 0.0f;
  for (int i = blockIdx.x * blockDim.x + threadIdx.x; i < (NROWS * DSIDE / 4); i += nt) {
    const float4 a2 = ((const float4*)l2)[i];
    const float4 a3 = ((const float4*)l3)[i];
    const float4 a4 = ((const float4*)l4)[i];
    float dx = a4.x - a2.x, dy = a4.y - a2.y, dz = a4.z - a2.z, dw = a4.w - a2.w;
    s2 += dx * dx + dy * dy + dz * dz + dw * dw;
    dx = a4.x - a3.x; dy = a4.y - a3.y; dz = a4.z - a3.z; dw = a4.w - a3.w;
    s3 += dx * dx + dy * dy + dz * dz + dw * dw;
  }
  s2 = wave_sum(s2);
  s3 = wave_sum(s3);
  __shared__ float red[8];
  const int wid = threadIdx.x >> 6, lane = threadIdx.x & 63;
  if (lane == 0) { red[wid] = s2; red[4 + wid] = s3; }
  __syncthreads();
  if (threadIdx.x == 0) {
    atomicAdd(&accw[3], red[0] + red[1] + red[2] + red[3]);
    atomicAdd(&accw[4], red[4] + red[5] + red[6] + red[7]);
  }
}

// ---------------- finalize ----------------
__global__ __launch_bounds__(64) void k_finalize(const float* __restrict__ accw,
                                                 float* __restrict__ out) {
  if (threadIdx.x == 0) {
    const float rank_loss = accw[0] / (float)NROWS;
    const float prec      = accw[1] / (float)NROWS;
    const float xent      = accw[2] / (float)NROWS;
    const float side      = sqrtf(accw[3]) + sqrtf(accw[4]);
    const float acc       = accw[5] / (float)NROWS;
    out[0] = rank_loss + xent + 0.1f * side;  // ALPHA=GAMMA=1, THETA=0.1
    out[1] = fmaxf(prec, acc);
  }
}

extern "C" void kernel_launch(void* const* d_in, const int* in_sizes, int n_in,
                              void* d_out, int out_size, void* d_ws, size_t ws_size,
                              hipStream_t stream) {
  (void)in_sizes; (void)n_in; (void)out_size; (void)ws_size;
  const float* cls = (const float*)d_in[0];
  const float* l2  = (const float*)d_in[1];
  const float* l3  = (const float*)d_in[2];
  const float* l4  = (const float*)d_in[3];
  const float* fea = (const float*)d_in[4];
  const int*   tgt = (const int*)d_in[5];
  float* out = (float*)d_out;

  // workspace layout (floats): [0..16) accumulators | sq[4096] | posw[4096*8] | part[4096*64]
  float* accw = (float*)d_ws;
  float* sq   = accw + 16;
  float* posw = sq + NROWS;
  float* part = posw + (size_t)NROWS * 8;

  k_zero<<<dim3(1), dim3(64), 0, stream>>>(accw);
  k_row_sq_acc<<<dim3(NROWS / 4), dim3(256), 0, stream>>>(fea, tgt, sq, accw);
  k_gemm_mine<<<dim3(8, 64), dim3(256), 0, stream>>>(fea, sq, posw, part);
  k_final_mine<<<dim3(NROWS / 256), dim3(256), 0, stream>>>(part, posw, accw);
  k_xent<<<dim3(NROWS / 4), dim3(256), 0, stream>>>(cls, tgt, accw);
  k_side<<<dim3(1024), dim3(256), 0, stream>>>(l2, l3, l4, accw);
  k_finalize<<<dim3(1), dim3(64), 0, stream>>>(accw, out);
}

// Round 2
// 369.172 us; speedup vs baseline: 1.4742x; 1.4742x over previous
//
#include <hip/hip_runtime.h>
#include <hip/hip_bf16.h>
#include <math.h>

// Problem constants (fixed-shape problem)
#define NROWS 4096
#define DFEA  512
#define NCLS  751
#define DSIDE 1024

typedef __attribute__((ext_vector_type(8))) short short8;
typedef __attribute__((ext_vector_type(4))) float f32x4;

__device__ __forceinline__ float wave_sum(float v) {
#pragma unroll
  for (int off = 32; off > 0; off >>= 1) v += __shfl_xor(v, off, 64);
  return v;
}

// async global->LDS, 16B per lane, wave-uniform LDS base + lane*16 (HW rule)
__device__ __forceinline__ void load_lds16(const void* g, void* l) {
  __builtin_amdgcn_global_load_lds((const __attribute__((address_space(1))) void*)g,
                                   (__attribute__((address_space(3))) void*)l, 16, 0, 0);
}

// branchless insert into ascending top-8 (drops the max)
__device__ __forceinline__ void ins8(float t8[8], float x) {
#pragma unroll
  for (int q = 0; q < 8; ++q) {
    const float lo = fminf(t8[q], x);
    x = fmaxf(t8[q], x);
    t8[q] = lo;
  }
}

#define CE(x, i, j) { const float ce_lo = fminf(x[i], x[j]); x[j] = fmaxf(x[i], x[j]); x[i] = ce_lo; }

// merge my ascending-8 with xor-partner's ascending-8, keep lowest 8 (sorted)
__device__ __forceinline__ void merge_sorted8(float a[8], int mask) {
  float b[8];
#pragma unroll
  for (int i = 0; i < 8; ++i) b[i] = __shfl_xor(a[i], mask, 64);
  float c[8];
#pragma unroll
  for (int i = 0; i < 8; ++i) c[i] = fminf(a[i], b[7 - i]);  // lowest-8, bitonic
  CE(c, 0, 4) CE(c, 1, 5) CE(c, 2, 6) CE(c, 3, 7)
  CE(c, 0, 2) CE(c, 1, 3) CE(c, 4, 6) CE(c, 5, 7)
  CE(c, 0, 1) CE(c, 2, 3) CE(c, 4, 5) CE(c, 6, 7)
#pragma unroll
  for (int i = 0; i < 8; ++i) a[i] = c[i];
}

__device__ __forceinline__ unsigned short bf16bits(float v) {
  union { __hip_bfloat16 b; unsigned short u; } cv;
  cv.b = __float2bfloat16(v);
  return cv.u;
}

// ---------------- accumulator zeroing ----------------
__global__ __launch_bounds__(64) void k_zero(float* __restrict__ accw) {
  if (threadIdx.x < 16) accw[threadIdx.x] = 0.0f;
}

// ---------------- per-row sum-of-squares + top1 accuracy ----------------
__global__ __launch_bounds__(256) void k_row_sq_acc(const float* __restrict__ fea,
                                                    const int* __restrict__ tgt,
                                                    float* __restrict__ sq,
                                                    float* __restrict__ accw) {
  const int lane = threadIdx.x & 63;
  const int wid  = threadIdx.x >> 6;
  const int row  = blockIdx.x * 4 + wid;
  const float* x = fea + (size_t)row * DFEA;
  float s = 0.0f, bv = -1e30f;
  int bi = 0;
#pragma unroll
  for (int q = 0; q < DFEA / 64; ++q) {
    const int c = lane + q * 64;
    const float v = x[c];
    s += v * v;
    if (v > bv) { bv = v; bi = c; }
  }
#pragma unroll
  for (int off = 32; off > 0; off >>= 1) {
    s += __shfl_xor(s, off, 64);
    const float ov = __shfl_xor(bv, off, 64);
    const int   oi = __shfl_xor(bi, off, 64);
    if (ov > bv || (ov == bv && oi < bi)) { bv = ov; bi = oi; }
  }
  __shared__ float red[4];
  if (lane == 0) {
    sq[row]  = s;
    red[wid] = (bi == tgt[row]) ? 1.0f : 0.0f;
  }
  __syncthreads();
  if (threadIdx.x == 0) atomicAdd(&accw[5], red[0] + red[1] + red[2] + red[3]);
}

// ---------------- split f32 -> (hi, lo) bf16 ----------------
__global__ __launch_bounds__(256) void k_split(const float* __restrict__ fea,
                                               unsigned short* __restrict__ Fhi,
                                               unsigned short* __restrict__ Flo) {
  const int i = blockIdx.x * 256 + threadIdx.x;  // float4 index, 524288 total
  const float4 x = ((const float4*)fea)[i];
  ushort4 h, l;
  float hf;
  h.x = bf16bits(x.x); hf = __bfloat162float(__ushort_as_bfloat16(h.x)); l.x = bf16bits(x.x - hf);
  h.y = bf16bits(x.y); hf = __bfloat162float(__ushort_as_bfloat16(h.y)); l.y = bf16bits(x.y - hf);
  h.z = bf16bits(x.z); hf = __bfloat162float(__ushort_as_bfloat16(h.z)); l.z = bf16bits(x.z - hf);
  h.w = bf16bits(x.w); hf = __bfloat162float(__ushort_as_bfloat16(h.w)); l.w = bf16bits(x.w - hf);
  ((ushort4*)Fhi)[i] = h;
  ((ushort4*)Flo)[i] = l;
}

// ---------------- MFMA distance GEMM + fused top-8 mining ----------------
// grid (32,32): bx = col block, by = row block. 128x128 tile, BK=64, 4 waves (2x2).
// dot = hi.hi + hi.lo + lo.hi over 3 K-segments of 512 (effective K=1536).
// Epilogue: d2 tile -> LDS (aliased over staging buffers) -> per-row top-8 negatives
// (positives excluded; diagonal blocks also emit the 8 positive d2 per row).
__global__ __launch_bounds__(256) void k_gemm_mfma(const unsigned short* __restrict__ Fhi,
                                                   const unsigned short* __restrict__ Flo,
                                                   const float* __restrict__ sq,
                                                   float* __restrict__ posw,
                                                   float* __restrict__ part) {
  const int bx = blockIdx.x, by = blockIdx.y;
  const int R0 = by * 128, C0 = bx * 128;
  const int tid = threadIdx.x;
  const int lane = tid & 63, wid = tid >> 6;
  const int wr = wid >> 1, wc = wid & 1;
  const int l15 = lane & 15, l4 = lane >> 4;

  __shared__ __attribute__((aligned(16))) char smem[33280];
  const __hip_bfloat16 (*As)[64] = (const __hip_bfloat16(*)[64])smem;           // 128x64, 16KB
  const __hip_bfloat16 (*Bs)[64] = (const __hip_bfloat16(*)[64])(smem + 16384); // 128x64, 16KB
  float (*dtile)[130] = (float(*)[130])smem;  // 64x130 f32, aliased (used post-GEMM)

  f32x4 acc[4][4];
#pragma unroll
  for (int m = 0; m < 4; ++m)
#pragma unroll
    for (int n = 0; n < 4; ++n) acc[m][n] = (f32x4){0.0f, 0.0f, 0.0f, 0.0f};

  for (int kt = 0; kt < 24; ++kt) {
    // K-segments: kt 0..7: A=hi,B=hi | 8..15: A=hi,B=lo | 16..23: A=lo,B=hi
    const unsigned short* Aseg = (kt < 16) ? Fhi : Flo;
    const unsigned short* Bseg = (kt >= 8 && kt < 16) ? Flo : Fhi;
    const int ks = (kt & 7) * 64;
    __syncthreads();  // previous iteration's ds_reads done before overwrite
#pragma unroll
    for (int i = 0; i < 4; ++i) {
      const int flat = i * 256 + tid;
      const int row = flat >> 3, c8 = flat & 7;
      load_lds16(Aseg + (size_t)(R0 + row) * DFEA + ks + c8 * 8,
                 smem + (i * 256 + wid * 64) * 16);
      load_lds16(Bseg + (size_t)(C0 + row) * DFEA + ks + c8 * 8,
                 smem + 16384 + (i * 256 + wid * 64) * 16);
    }
    __syncthreads();  // vmcnt(0) drain + barrier (compiler-inserted)
#pragma unroll
    for (int kk = 0; kk < 2; ++kk) {
      short8 af[4], bf[4];
#pragma unroll
      for (int m = 0; m < 4; ++m)
        af[m] = *(const short8*)&As[wr * 64 + m * 16 + l15][kk * 32 + l4 * 8];
#pragma unroll
      for (int n = 0; n < 4; ++n)
        bf[n] = *(const short8*)&Bs[wc * 64 + n * 16 + l15][kk * 32 + l4 * 8];
#pragma unroll
      for (int m = 0; m < 4; ++m)
#pragma unroll
        for (int n = 0; n < 4; ++n)
          acc[m][n] = __builtin_amdgcn_mfma_f32_16x16x32_bf16(af[m], bf[n], acc[m][n], 0, 0, 0);
    }
  }

  // epilogue: d2 = sq_i + sq_j - 2*dot, then per-row top-8 negative mining
  float sqi[4][4], sqj[4];
#pragma unroll
  for (int m = 0; m < 4; ++m)
#pragma unroll
    for (int r = 0; r < 4; ++r) sqi[m][r] = sq[R0 + wr * 64 + m * 16 + l4 * 4 + r];
#pragma unroll
  for (int n = 0; n < 4; ++n) sqj[n] = sq[C0 + wc * 64 + n * 16 + l15];

  const bool diag = (bx == by);

  for (int h = 0; h < 2; ++h) {  // two 64-row halves share the 33KB dtile
    __syncthreads();             // prior phase's LDS reads done
    if (wr == h) {
      // C/D layout (verified m89/m91): col = lane&15, row = (lane>>4)*4 + reg
#pragma unroll
      for (int m = 0; m < 4; ++m)
#pragma unroll
        for (int n = 0; n < 4; ++n)
#pragma unroll
          for (int r = 0; r < 4; ++r)
            dtile[m * 16 + l4 * 4 + r][wc * 64 + n * 16 + l15] =
                sqi[m][r] + sqj[n] - 2.0f * acc[m][n][r];
    }
    __syncthreads();
    // 4 threads per row, 32 cols each
    const int r = tid >> 2, q = tid & 3;
    const int rg = R0 + h * 64 + r;
    float t8[8];
#pragma unroll
    for (int i = 0; i < 8; ++i) t8[i] = 1e30f;
    if (diag) {
      for (int s = 0; s < 32; ++s) {
        const int cg = C0 + q * 32 + s;
        const float v = dtile[r][q * 32 + s];
        if (((rg ^ cg) >> 3) == 0) posw[(size_t)rg * 8 + (cg & 7)] = v;  // same identity
        else ins8(t8, v);
      }
    } else {
      for (int s = 0; s < 32; ++s) ins8(t8, dtile[r][q * 32 + s]);
    }
    merge_sorted8(t8, 1);
    merge_sorted8(t8, 2);
    if (q == 0) {
      const float4 o0 = {t8[0], t8[1], t8[2], t8[3]};
      const float4 o1 = {t8[4], t8[5], t8[6], t8[7]};
      *(float4*)&part[(size_t)rg * 256 + bx * 8] = o0;
      *(float4*)&part[(size_t)rg * 256 + bx * 8 + 4] = o1;
    }
  }
}

// ---------------- final merge (wave per row) + rank loss ----------------
__global__ __launch_bounds__(256) void k_final2(const float* __restrict__ part,
                                                const float* __restrict__ posw,
                                                float* __restrict__ accw) {
  const int lane = threadIdx.x & 63, w = threadIdx.x >> 6;
  const int row = blockIdx.x * 4 + w;
  float a[8];
  if (lane < 32) {
    const float4 v0 = *(const float4*)&part[(size_t)row * 256 + lane * 8];
    const float4 v1 = *(const float4*)&part[(size_t)row * 256 + lane * 8 + 4];
    a[0] = v0.x; a[1] = v0.y; a[2] = v0.z; a[3] = v0.w;
    a[4] = v1.x; a[5] = v1.y; a[6] = v1.z; a[7] = v1.w;
  } else {
#pragma unroll
    for (int i = 0; i < 8; ++i) a[i] = 1e30f;
  }
  merge_sorted8(a, 1);
  merge_sorted8(a, 2);
  merge_sorted8(a, 4);
  merge_sorted8(a, 8);
  merge_sorted8(a, 16);  // lanes 0..31 now all hold global top-8 (ascending d2)
  if (lane == 0) {
    float nd[8];
#pragma unroll
    for (int i = 0; i < 8; ++i) nd[i] = sqrtf(fmaxf(a[i], 1e-12f));
    float s8[8];
#pragma unroll
    for (int i = 0; i < 8; ++i) s8[i] = 1e30f;
#pragma unroll
    for (int i = 0; i < 8; ++i)
      ins8(s8, sqrtf(fmaxf(posw[(size_t)row * 8 + i], 1e-12f)));  // positives ascending
    int ip = 0, in_ = 0;
#pragma unroll
    for (int s = 0; s < 8; ++s) {  // m = #negatives among 8 smallest of union
      const bool takeNeg = (in_ < 8) && (ip >= 8 || nd[in_] < s8[ip]);
      if (takeNeg) ++in_; else ++ip;
    }
    const int m = in_;
    float loss = 0.0f;
    const float n0 = nd[0];
    for (int k = 0; k < m; ++k)
      loss += (float)(m - k) * expf((n0 - nd[k]) / (n0 + 1e-12f)) * (s8[7 - k] - nd[k]) + 0.5f;
    atomicAdd(&accw[0], loss);
    atomicAdd(&accw[1], (m == 0) ? 1.0f : 0.0f);
  }
}

// ---------------- cross entropy (one wave per row) ----------------
__global__ __launch_bounds__(256) void k_xent(const float* __restrict__ cls,
                                              const int* __restrict__ tgt,
                                              float* __restrict__ accw) {
  const int lane = threadIdx.x & 63, wid = threadIdx.x >> 6;
  const int row = blockIdx.x * 4 + wid;
  const float* x = cls + (size_t)row * NCLS;
  float mx = -1e30f;
  for (int c = lane; c < NCLS; c += 64) mx = fmaxf(mx, x[c]);
#pragma unroll
  for (int off = 32; off > 0; off >>= 1) mx = fmaxf(mx, __shfl_xor(mx, off, 64));
  float se = 0.0f;
  for (int c = lane; c < NCLS; c += 64) se += expf(x[c] - mx);
  se = wave_sum(se);
  __shared__ float red[4];
  if (lane == 0) red[wid] = logf(se) + mx - x[tgt[row]];
  __syncthreads();
  if (threadIdx.x == 0) atomicAdd(&accw[2], red[0] + red[1] + red[2] + red[3]);
}

// ---------------- side losses ----------------
__global__ __launch_bounds__(256) void k_side(const float* __restrict__ l2,
                                              const float* __restrict__ l3,
                                              const float* __restrict__ l4,
                                              float* __restrict__ accw) {
  const int nt = gridDim.x * blockDim.x;
  float s2 = 0.0f, s3 = 0.0f;
  for (int i = blockIdx.x * blockDim.x + threadIdx.x; i < (NROWS * DSIDE / 4); i += nt) {
    const float4 a2 = ((const float4*)l2)[i];
    const float4 a3 = ((const float4*)l3)[i];
    const float4 a4 = ((const float4*)l4)[i];
    float dx = a4.x - a2.x, dy = a4.y - a2.y, dz = a4.z - a2.z, dw = a4.w - a2.w;
    s2 += dx * dx + dy * dy + dz * dz + dw * dw;
    dx = a4.x - a3.x; dy = a4.y - a3.y; dz = a4.z - a3.z; dw = a4.w - a3.w;
    s3 += dx * dx + dy * dy + dz * dz + dw * dw;
  }
  s2 = wave_sum(s2);
  s3 = wave_sum(s3);
  __shared__ float red[8];
  const int wid = threadIdx.x >> 6, lane = threadIdx.x & 63;
  if (lane == 0) { red[wid] = s2; red[4 + wid] = s3; }
  __syncthreads();
  if (threadIdx.x == 0) {
    atomicAdd(&accw[3], red[0] + red[1] + red[2] + red[3]);
    atomicAdd(&accw[4], red[4] + red[5] + red[6] + red[7]);
  }
}

// ---------------- finalize ----------------
__global__ __launch_bounds__(64) void k_finalize(const float* __restrict__ accw,
                                                 float* __restrict__ out) {
  if (threadIdx.x == 0) {
    const float rank_loss = accw[0] / (float)NROWS;
    const float prec      = accw[1] / (float)NROWS;
    const float xent      = accw[2] / (float)NROWS;
    const float side      = sqrtf(accw[3]) + sqrtf(accw[4]);
    const float acc       = accw[5] / (float)NROWS;
    out[0] = rank_loss + xent + 0.1f * side;  // ALPHA=GAMMA=1, THETA=0.1
    out[1] = fmaxf(prec, acc);
  }
}

extern "C" void kernel_launch(void* const* d_in, const int* in_sizes, int n_in,
                              void* d_out, int out_size, void* d_ws, size_t ws_size,
                              hipStream_t stream) {
  (void)in_sizes; (void)n_in; (void)out_size; (void)ws_size;
  const float* cls = (const float*)d_in[0];
  const float* l2  = (const float*)d_in[1];
  const float* l3  = (const float*)d_in[2];
  const float* l4  = (const float*)d_in[3];
  const float* fea = (const float*)d_in[4];
  const int*   tgt = (const int*)d_in[5];
  float* out = (float*)d_out;

  // ws layout (floats): accw[16] | sq[4096] | Fhi (4096x512 bf16 = 1M floats)
  //                     | Flo (1M floats) | part (4096*256) | posw (4096*8)
  float* accw = (float*)d_ws;
  float* sq   = accw + 16;
  unsigned short* Fhi = (unsigned short*)(sq + NROWS);
  unsigned short* Flo = Fhi + (size_t)NROWS * DFEA;
  float* part = (float*)(Flo + (size_t)NROWS * DFEA);
  float* posw = part + (size_t)NROWS * 256;

  k_zero<<<dim3(1), dim3(64), 0, stream>>>(accw);
  k_row_sq_acc<<<dim3(NROWS / 4), dim3(256), 0, stream>>>(fea, tgt, sq, accw);
  k_split<<<dim3(NROWS * DFEA / 4 / 256), dim3(256), 0, stream>>>(fea, Fhi, Flo);
  k_gemm_mfma<<<dim3(32, 32), dim3(256), 0, stream>>>(Fhi, Flo, sq, posw, part);
  k_final2<<<dim3(NROWS / 4), dim3(256), 0, stream>>>(part, posw, accw);
  k_xent<<<dim3(NROWS / 4), dim3(256), 0, stream>>>(cls, tgt, accw);
  k_side<<<dim3(1024), dim3(256), 0, stream>>>(l2, l3, l4, accw);
  k_finalize<<<dim3(1), dim3(64), 0, stream>>>(accw, out);
}

// Round 3
// 221.119 us; speedup vs baseline: 2.4613x; 1.6696x over previous
//
#include <hip/hip_runtime.h>
#include <hip/hip_bf16.h>
#include <math.h>

// Problem constants (fixed-shape problem)
#define NROWS 4096
#define DFEA  512
#define NCLS  751
#define DSIDE 1024

typedef __attribute__((ext_vector_type(8))) short short8;
typedef __attribute__((ext_vector_type(4))) float f32x4;

__device__ __forceinline__ float wave_sum(float v) {
#pragma unroll
  for (int off = 32; off > 0; off >>= 1) v += __shfl_xor(v, off, 64);
  return v;
}

// async global->LDS, 16B per lane, wave-uniform LDS base + lane*16 (HW rule)
__device__ __forceinline__ void load_lds16(const void* g, void* l) {
  __builtin_amdgcn_global_load_lds((const __attribute__((address_space(1))) void*)g,
                                   (__attribute__((address_space(3))) void*)l, 16, 0, 0);
}

// branchless insert into ascending top-8 (drops the max)
__device__ __forceinline__ void ins8(float t8[8], float x) {
#pragma unroll
  for (int q = 0; q < 8; ++q) {
    const float lo = fminf(t8[q], x);
    x = fmaxf(t8[q], x);
    t8[q] = lo;
  }
}

#define CE(x, i, j) { const float ce_lo = fminf(x[i], x[j]); x[j] = fmaxf(x[i], x[j]); x[i] = ce_lo; }

// merge my ascending-8 with xor-partner's ascending-8, keep lowest 8 (sorted)
__device__ __forceinline__ void merge_sorted8(float a[8], int mask) {
  float b[8];
#pragma unroll
  for (int i = 0; i < 8; ++i) b[i] = __shfl_xor(a[i], mask, 64);
  float c[8];
#pragma unroll
  for (int i = 0; i < 8; ++i) c[i] = fminf(a[i], b[7 - i]);  // lowest-8, bitonic
  CE(c, 0, 4) CE(c, 1, 5) CE(c, 2, 6) CE(c, 3, 7)
  CE(c, 0, 2) CE(c, 1, 3) CE(c, 4, 6) CE(c, 5, 7)
  CE(c, 0, 1) CE(c, 2, 3) CE(c, 4, 5) CE(c, 6, 7)
#pragma unroll
  for (int i = 0; i < 8; ++i) a[i] = c[i];
}

__device__ __forceinline__ unsigned short bf16bits(float v) {
  union { __hip_bfloat16 b; unsigned short u; } cv;
  cv.b = __float2bfloat16(v);
  return cv.u;
}

// ---------------- per-row sum-of-squares + top1 accuracy ----------------
// one wave per row; 4 rows per block; block partial -> pa[blockIdx]
__global__ __launch_bounds__(256) void k_row_sq_acc(const float* __restrict__ fea,
                                                    const int* __restrict__ tgt,
                                                    float* __restrict__ sq,
                                                    float* __restrict__ pa) {
  const int lane = threadIdx.x & 63;
  const int wid  = threadIdx.x >> 6;
  const int row  = blockIdx.x * 4 + wid;
  const float* x = fea + (size_t)row * DFEA;
  float s = 0.0f, bv = -1e30f;
  int bi = 0;
#pragma unroll
  for (int q = 0; q < DFEA / 64; ++q) {
    const int c = lane + q * 64;
    const float v = x[c];
    s += v * v;
    if (v > bv) { bv = v; bi = c; }
  }
#pragma unroll
  for (int off = 32; off > 0; off >>= 1) {
    s += __shfl_xor(s, off, 64);
    const float ov = __shfl_xor(bv, off, 64);
    const int   oi = __shfl_xor(bi, off, 64);
    if (ov > bv || (ov == bv && oi < bi)) { bv = ov; bi = oi; }
  }
  __shared__ float red[4];
  if (lane == 0) {
    sq[row]  = s;
    red[wid] = (bi == tgt[row]) ? 1.0f : 0.0f;
  }
  __syncthreads();
  if (threadIdx.x == 0) pa[blockIdx.x] = red[0] + red[1] + red[2] + red[3];
}

// ---------------- split f32 -> (hi, lo) bf16 ----------------
__global__ __launch_bounds__(256) void k_split(const float* __restrict__ fea,
                                               unsigned short* __restrict__ Fhi,
                                               unsigned short* __restrict__ Flo) {
  const int i = blockIdx.x * 256 + threadIdx.x;  // float4 index, 524288 total
  const float4 x = ((const float4*)fea)[i];
  ushort4 h, l;
  float hf;
  h.x = bf16bits(x.x); hf = __bfloat162float(__ushort_as_bfloat16(h.x)); l.x = bf16bits(x.x - hf);
  h.y = bf16bits(x.y); hf = __bfloat162float(__ushort_as_bfloat16(h.y)); l.y = bf16bits(x.y - hf);
  h.z = bf16bits(x.z); hf = __bfloat162float(__ushort_as_bfloat16(h.z)); l.z = bf16bits(x.z - hf);
  h.w = bf16bits(x.w); hf = __bfloat162float(__ushort_as_bfloat16(h.w)); l.w = bf16bits(x.w - hf);
  ((ushort4*)Fhi)[i] = h;
  ((ushort4*)Flo)[i] = l;
}

// ---------------- MFMA distance GEMM + fused top-8 mining ----------------
// grid (32,32): bx = col block, by = row block. 128x128 tile, BK=64, 4 waves (2x2).
// dot = hi.hi + hi.lo + lo.hi over 3 K-segments of 512 (effective K=1536).
__global__ __launch_bounds__(256) void k_gemm_mfma(const unsigned short* __restrict__ Fhi,
                                                   const unsigned short* __restrict__ Flo,
                                                   const float* __restrict__ sq,
                                                   float* __restrict__ posw,
                                                   float* __restrict__ part) {
  const int bx = blockIdx.x, by = blockIdx.y;
  const int R0 = by * 128, C0 = bx * 128;
  const int tid = threadIdx.x;
  const int lane = tid & 63, wid = tid >> 6;
  const int wr = wid >> 1, wc = wid & 1;
  const int l15 = lane & 15, l4 = lane >> 4;

  __shared__ __attribute__((aligned(16))) char smem[33280];
  const __hip_bfloat16 (*As)[64] = (const __hip_bfloat16(*)[64])smem;           // 128x64, 16KB
  const __hip_bfloat16 (*Bs)[64] = (const __hip_bfloat16(*)[64])(smem + 16384); // 128x64, 16KB
  float (*dtile)[130] = (float(*)[130])smem;  // 64x130 f32, aliased (used post-GEMM)

  f32x4 acc[4][4];
#pragma unroll
  for (int m = 0; m < 4; ++m)
#pragma unroll
    for (int n = 0; n < 4; ++n) acc[m][n] = (f32x4){0.0f, 0.0f, 0.0f, 0.0f};

  for (int kt = 0; kt < 24; ++kt) {
    // K-segments: kt 0..7: A=hi,B=hi | 8..15: A=hi,B=lo | 16..23: A=lo,B=hi
    const unsigned short* Aseg = (kt < 16) ? Fhi : Flo;
    const unsigned short* Bseg = (kt >= 8 && kt < 16) ? Flo : Fhi;
    const int ks = (kt & 7) * 64;
    __syncthreads();  // previous iteration's ds_reads done before overwrite
#pragma unroll
    for (int i = 0; i < 4; ++i) {
      const int flat = i * 256 + tid;
      const int row = flat >> 3, c8 = flat & 7;
      load_lds16(Aseg + (size_t)(R0 + row) * DFEA + ks + c8 * 8,
                 smem + (i * 256 + wid * 64) * 16);
      load_lds16(Bseg + (size_t)(C0 + row) * DFEA + ks + c8 * 8,
                 smem + 16384 + (i * 256 + wid * 64) * 16);
    }
    __syncthreads();  // vmcnt(0) drain + barrier (compiler-inserted)
#pragma unroll
    for (int kk = 0; kk < 2; ++kk) {
      short8 af[4], bf[4];
#pragma unroll
      for (int m = 0; m < 4; ++m)
        af[m] = *(const short8*)&As[wr * 64 + m * 16 + l15][kk * 32 + l4 * 8];
#pragma unroll
      for (int n = 0; n < 4; ++n)
        bf[n] = *(const short8*)&Bs[wc * 64 + n * 16 + l15][kk * 32 + l4 * 8];
#pragma unroll
      for (int m = 0; m < 4; ++m)
#pragma unroll
        for (int n = 0; n < 4; ++n)
          acc[m][n] = __builtin_amdgcn_mfma_f32_16x16x32_bf16(af[m], bf[n], acc[m][n], 0, 0, 0);
    }
  }

  // epilogue: d2 = sq_i + sq_j - 2*dot, then per-row top-8 negative mining
  float sqi[4][4], sqj[4];
#pragma unroll
  for (int m = 0; m < 4; ++m)
#pragma unroll
    for (int r = 0; r < 4; ++r) sqi[m][r] = sq[R0 + wr * 64 + m * 16 + l4 * 4 + r];
#pragma unroll
  for (int n = 0; n < 4; ++n) sqj[n] = sq[C0 + wc * 64 + n * 16 + l15];

  const bool diag = (bx == by);

  for (int h = 0; h < 2; ++h) {  // two 64-row halves share the 33KB dtile
    __syncthreads();             // prior phase's LDS reads done
    if (wr == h) {
      // C/D layout (verified m89/m91): col = lane&15, row = (lane>>4)*4 + reg
#pragma unroll
      for (int m = 0; m < 4; ++m)
#pragma unroll
        for (int n = 0; n < 4; ++n)
#pragma unroll
          for (int r = 0; r < 4; ++r)
            dtile[m * 16 + l4 * 4 + r][wc * 64 + n * 16 + l15] =
                sqi[m][r] + sqj[n] - 2.0f * acc[m][n][r];
    }
    __syncthreads();
    // 4 threads per row, 32 cols each
    const int r = tid >> 2, q = tid & 3;
    const int rg = R0 + h * 64 + r;
    float t8[8];
#pragma unroll
    for (int i = 0; i < 8; ++i) t8[i] = 1e30f;
    if (diag) {
      for (int s = 0; s < 32; ++s) {
        const int cg = C0 + q * 32 + s;
        const float v = dtile[r][q * 32 + s];
        if (((rg ^ cg) >> 3) == 0) posw[(size_t)rg * 8 + (cg & 7)] = v;  // same identity
        else ins8(t8, v);
      }
    } else {
      for (int s = 0; s < 32; ++s) ins8(t8, dtile[r][q * 32 + s]);
    }
    merge_sorted8(t8, 1);
    merge_sorted8(t8, 2);
    if (q == 0) {
      const float4 o0 = {t8[0], t8[1], t8[2], t8[3]};
      const float4 o1 = {t8[4], t8[5], t8[6], t8[7]};
      *(float4*)&part[(size_t)rg * 256 + bx * 8] = o0;
      *(float4*)&part[(size_t)rg * 256 + bx * 8 + 4] = o1;
    }
  }
}

// ---------------- final merge (wave per row) + rank loss ----------------
// block partials -> pl[blockIdx] (loss), pc[blockIdx] (correct count). No atomics.
__global__ __launch_bounds__(256) void k_final2(const float* __restrict__ part,
                                                const float* __restrict__ posw,
                                                float* __restrict__ pl,
                                                float* __restrict__ pc) {
  const int lane = threadIdx.x & 63, w = threadIdx.x >> 6;
  const int row = blockIdx.x * 4 + w;
  float a[8];
  if (lane < 32) {
    const float4 v0 = *(const float4*)&part[(size_t)row * 256 + lane * 8];
    const float4 v1 = *(const float4*)&part[(size_t)row * 256 + lane * 8 + 4];
    a[0] = v0.x; a[1] = v0.y; a[2] = v0.z; a[3] = v0.w;
    a[4] = v1.x; a[5] = v1.y; a[6] = v1.z; a[7] = v1.w;
  } else {
#pragma unroll
    for (int i = 0; i < 8; ++i) a[i] = 1e30f;
  }
  merge_sorted8(a, 1);
  merge_sorted8(a, 2);
  merge_sorted8(a, 4);
  merge_sorted8(a, 8);
  merge_sorted8(a, 16);  // lanes 0..31 now all hold global top-8 (ascending d2)
  __shared__ float red[8];
  if (lane == 0) {
    float nd[8];
#pragma unroll
    for (int i = 0; i < 8; ++i) nd[i] = sqrtf(fmaxf(a[i], 1e-12f));
    float s8[8];
#pragma unroll
    for (int i = 0; i < 8; ++i) s8[i] = 1e30f;
#pragma unroll
    for (int i = 0; i < 8; ++i)
      ins8(s8, sqrtf(fmaxf(posw[(size_t)row * 8 + i], 1e-12f)));  // positives ascending
    int ip = 0, in_ = 0;
#pragma unroll
    for (int s = 0; s < 8; ++s) {  // m = #negatives among 8 smallest of union
      const bool takeNeg = (in_ < 8) && (ip >= 8 || nd[in_] < s8[ip]);
      if (takeNeg) ++in_; else ++ip;
    }
    const int m = in_;
    float loss = 0.0f;
    const float n0 = nd[0];
    for (int k = 0; k < m; ++k)
      loss += (float)(m - k) * expf((n0 - nd[k]) / (n0 + 1e-12f)) * (s8[7 - k] - nd[k]) + 0.5f;
    red[w] = loss;
    red[4 + w] = (m == 0) ? 1.0f : 0.0f;
  }
  __syncthreads();
  if (threadIdx.x == 0) {
    pl[blockIdx.x] = red[0] + red[1] + red[2] + red[3];
    pc[blockIdx.x] = red[4] + red[5] + red[6] + red[7];
  }
}

// ---------------- cross entropy (one wave per row) ----------------
__global__ __launch_bounds__(256) void k_xent(const float* __restrict__ cls,
                                              const int* __restrict__ tgt,
                                              float* __restrict__ px) {
  const int lane = threadIdx.x & 63, wid = threadIdx.x >> 6;
  const int row = blockIdx.x * 4 + wid;
  const float* x = cls + (size_t)row * NCLS;
  float mx = -1e30f;
  for (int c = lane; c < NCLS; c += 64) mx = fmaxf(mx, x[c]);
#pragma unroll
  for (int off = 32; off > 0; off >>= 1) mx = fmaxf(mx, __shfl_xor(mx, off, 64));
  float se = 0.0f;
  for (int c = lane; c < NCLS; c += 64) se += expf(x[c] - mx);
  se = wave_sum(se);
  __shared__ float red[4];
  if (lane == 0) red[wid] = logf(se) + mx - x[tgt[row]];
  __syncthreads();
  if (threadIdx.x == 0) px[blockIdx.x] = red[0] + red[1] + red[2] + red[3];
}

// ---------------- side losses ----------------
__global__ __launch_bounds__(256) void k_side(const float* __restrict__ l2,
                                              const float* __restrict__ l3,
                                              const float* __restrict__ l4,
                                              float* __restrict__ ps2,
                                              float* __restrict__ ps3) {
  const int nt = gridDim.x * blockDim.x;
  float s2 = 0.0f, s3 = 0.0f;
  for (int i = blockIdx.x * blockDim.x + threadIdx.x; i < (NROWS * DSIDE / 4); i += nt) {
    const float4 a2 = ((const float4*)l2)[i];
    const float4 a3 = ((const float4*)l3)[i];
    const float4 a4 = ((const float4*)l4)[i];
    float dx = a4.x - a2.x, dy = a4.y - a2.y, dz = a4.z - a2.z, dw = a4.w - a2.w;
    s2 += dx * dx + dy * dy + dz * dz + dw * dw;
    dx = a4.x - a3.x; dy = a4.y - a3.y; dz = a4.z - a3.z; dw = a4.w - a3.w;
    s3 += dx * dx + dy * dy + dz * dz + dw * dw;
  }
  s2 = wave_sum(s2);
  s3 = wave_sum(s3);
  __shared__ float red[8];
  const int wid = threadIdx.x >> 6, lane = threadIdx.x & 63;
  if (lane == 0) { red[wid] = s2; red[4 + wid] = s3; }
  __syncthreads();
  if (threadIdx.x == 0) {
    ps2[blockIdx.x] = red[0] + red[1] + red[2] + red[3];
    ps3[blockIdx.x] = red[4] + red[5] + red[6] + red[7];
  }
}

// ---------------- finalize: sum the 6 partial arrays (1024 each) ----------------
__global__ __launch_bounds__(256) void k_finalize(const float* __restrict__ pl,
                                                  const float* __restrict__ pc,
                                                  const float* __restrict__ px,
                                                  const float* __restrict__ pa,
                                                  const float* __restrict__ ps2,
                                                  const float* __restrict__ ps3,
                                                  float* __restrict__ out) {
  const int t = threadIdx.x;
  float s[6] = {0, 0, 0, 0, 0, 0};
  for (int i = t; i < 1024; i += 256) {
    s[0] += pl[i]; s[1] += pc[i]; s[2] += px[i];
    s[3] += pa[i]; s[4] += ps2[i]; s[5] += ps3[i];
  }
  __shared__ float red[6][4];
  const int lane = t & 63, w = t >> 6;
#pragma unroll
  for (int j = 0; j < 6; ++j) {
    s[j] = wave_sum(s[j]);
    if (lane == 0) red[j][w] = s[j];
  }
  __syncthreads();
  if (t == 0) {
    const float rank_loss = (red[0][0] + red[0][1] + red[0][2] + red[0][3]) / (float)NROWS;
    const float prec      = (red[1][0] + red[1][1] + red[1][2] + red[1][3]) / (float)NROWS;
    const float xent      = (red[2][0] + red[2][1] + red[2][2] + red[2][3]) / (float)NROWS;
    const float acc       = (red[3][0] + red[3][1] + red[3][2] + red[3][3]) / (float)NROWS;
    const float side      = sqrtf(red[4][0] + red[4][1] + red[4][2] + red[4][3]) +
                            sqrtf(red[5][0] + red[5][1] + red[5][2] + red[5][3]);
    out[0] = rank_loss + xent + 0.1f * side;  // ALPHA=GAMMA=1, THETA=0.1
    out[1] = fmaxf(prec, acc);
  }
}

extern "C" void kernel_launch(void* const* d_in, const int* in_sizes, int n_in,
                              void* d_out, int out_size, void* d_ws, size_t ws_size,
                              hipStream_t stream) {
  (void)in_sizes; (void)n_in; (void)out_size; (void)ws_size;
  const float* cls = (const float*)d_in[0];
  const float* l2  = (const float*)d_in[1];
  const float* l3  = (const float*)d_in[2];
  const float* l4  = (const float*)d_in[3];
  const float* fea = (const float*)d_in[4];
  const int*   tgt = (const int*)d_in[5];
  float* out = (float*)d_out;

  // ws layout (floats): sq[4096] | Fhi (1M) | Flo (1M) | part (1M) | posw (32K)
  //                     | pl[1024] | pc[1024] | px[1024] | pa[1024] | ps2[1024] | ps3[1024]
  float* sq   = (float*)d_ws;
  unsigned short* Fhi = (unsigned short*)(sq + NROWS);
  unsigned short* Flo = Fhi + (size_t)NROWS * DFEA;
  float* part = (float*)(Flo + (size_t)NROWS * DFEA);
  float* posw = part + (size_t)NROWS * 256;
  float* pl   = posw + (size_t)NROWS * 8;
  float* pc   = pl + 1024;
  float* px   = pc + 1024;
  float* pa   = px + 1024;
  float* ps2  = pa + 1024;
  float* ps3  = ps2 + 1024;

  k_row_sq_acc<<<dim3(NROWS / 4), dim3(256), 0, stream>>>(fea, tgt, sq, pa);
  k_split<<<dim3(NROWS * DFEA / 4 / 256), dim3(256), 0, stream>>>(fea, Fhi, Flo);
  k_gemm_mfma<<<dim3(32, 32), dim3(256), 0, stream>>>(Fhi, Flo, sq, posw, part);
  k_final2<<<dim3(NROWS / 4), dim3(256), 0, stream>>>(part, posw, pl, pc);
  k_xent<<<dim3(NROWS / 4), dim3(256), 0, stream>>>(cls, tgt, px);
  k_side<<<dim3(1024), dim3(256), 0, stream>>>(l2, l3, l4, ps2, ps3);
  k_finalize<<<dim3(1), dim3(256), 0, stream>>>(pl, pc, px, pa, ps2, ps3, out);
}